// Round 7
// baseline (187.165 us; speedup 1.0000x reference)
//
#include <hip/hip_runtime.h>
#include <hip/hip_bf16.h>

#define TOT 66560
#define NQ 1024
#define DIM 512
#define K_SEL 3328
#define HST 260  // per-wave u8-hist copy stride (u32)

typedef short bf16x8 __attribute__((ext_vector_type(8)));
typedef float f32x4 __attribute__((ext_vector_type(4)));

__device__ __forceinline__ unsigned short f2bf(float f) {
  unsigned int u = __float_as_uint(f);
  unsigned int r = u + 0x7FFFu + ((u >> 16) & 1u);
  return (unsigned short)(r >> 16);
}

__device__ __forceinline__ void gload_lds16(const unsigned short* g, unsigned short* l) {
  __builtin_amdgcn_global_load_lds(
      (const __attribute__((address_space(1))) unsigned int*)g,
      (__attribute__((address_space(3))) unsigned int*)l, 16, 0, 0);
}

// fence-protected barrier (rule #18)
#define FENCE_BAR()                    \
  do {                                 \
    __builtin_amdgcn_sched_barrier(0); \
    __builtin_amdgcn_s_barrier();      \
    __builtin_amdgcn_sched_barrier(0); \
  } while (0)

// ---------------- normalize rows -> bf16 feature matrix F (TOT x 512) -----
__global__ __launch_bounds__(256) void norm_kernel(
    const float* __restrict__ inputs, const float* __restrict__ bank,
    unsigned short* __restrict__ F) {
  int row = blockIdx.x * 4 + (threadIdx.x >> 6);
  int lane = threadIdx.x & 63;
  const float* src = (row < NQ) ? (inputs + (size_t)row * DIM)
                                : (bank + (size_t)(row - NQ) * DIM);
  const float4 a = *(const float4*)(src + lane * 8);
  const float4 b = *(const float4*)(src + lane * 8 + 4);
  float ss = a.x * a.x + a.y * a.y + a.z * a.z + a.w * a.w +
             b.x * b.x + b.y * b.y + b.z * b.z + b.w * b.w;
#pragma unroll
  for (int off = 1; off < 64; off <<= 1) ss += __shfl_xor(ss, off);
  float inv = 1.0f / fmaxf(sqrtf(ss), 1e-12f);
  bf16x8 o;
  o[0] = (short)f2bf(a.x * inv);
  o[1] = (short)f2bf(a.y * inv);
  o[2] = (short)f2bf(a.z * inv);
  o[3] = (short)f2bf(a.w * inv);
  o[4] = (short)f2bf(b.x * inv);
  o[5] = (short)f2bf(b.y * inv);
  o[6] = (short)f2bf(b.z * inv);
  o[7] = (short)f2bf(b.w * inv);
  *(bf16x8*)(F + (size_t)row * DIM + lane * 8) = o;
}

// ---------------- pack labels to 4-bit nibbles (C=7 fits) -----------------
__global__ __launch_bounds__(256) void pack_kernel(
    const int* __restrict__ gt, const int* __restrict__ bl,
    unsigned int* __restrict__ lab4) {
  int i = blockIdx.x * 256 + threadIdx.x;  // packs labels [8i, 8i+8)
  if (i >= TOT / 8) return;
  unsigned int w = 0;
#pragma unroll
  for (int e = 0; e < 8; ++e) {
    int c = i * 8 + e;
    int l = (c < NQ) ? gt[c] : bl[c - NQ];
    w |= ((unsigned int)l & 0xFu) << (4 * e);
  }
  lab4[i] = w;
}

// ---------------- S = quantize_u8(F[0:1024] * F^T) ------------------------
// 128(M)x256(N) tile, 4 waves (2x2), each wave 64x128 -> acc[4][8], 32 MFMA
// per 32-K step. 3-deep global_load_lds pipeline (counted vmcnt(12)),
// chunk-XOR swizzle, epilogue quantizes to u8 bucket keys (self -> 0).
__global__ __launch_bounds__(256) void gemm_kernel(
    const unsigned short* __restrict__ F, unsigned char* __restrict__ S) {
  __shared__ unsigned short smem[36864];  // 3 x (At[128*32]=4096 | Bt[256*32]=8192)

  // XCD-aware swizzle: 2080 blocks, 8 XCDs, 260 per XCD, bm fastest.
  int wgid = blockIdx.x;
  int xcd = wgid & 7;
  int local = wgid >> 3;
  int gid = xcd * 260 + local;
  int bm = gid & 7;    // row tile 0..7 (fastest: 8 blocks share a B panel)
  int bn = gid >> 3;   // col tile 0..259

  int tid = threadIdx.x;
  int lane = tid & 63, wave = tid >> 6;
  int wr = wave >> 1, wc = wave & 1;

  f32x4 acc[4][8];
#pragma unroll
  for (int m = 0; m < 4; ++m)
#pragma unroll
    for (int n = 0; n < 8; ++n) acc[m][n] = (f32x4){0.f, 0.f, 0.f, 0.f};

  int rowA0 = bm * 128;
  int rowB0 = bn * 256;
  int lr = lane >> 2;       // staged row within 16-row chunk
  int lc = lane & 3;        // logical 16B chunk
  int ssw = (lr >> 1) & 3;  // stage swizzle (row&15 parity group)
  int pc = (lc ^ ssw) * 8;  // pre-swizzled global chunk offset (shorts)

  // wave w stages A rows [32w,32w+32) and B rows [64w,64w+64)
  const unsigned short* gA0 = F + (size_t)(rowA0 + wave * 32 + lr) * DIM + pc;
  const unsigned short* gA1 = gA0 + (size_t)16 * DIM;
  const unsigned short* gB0 = F + (size_t)(rowB0 + wave * 64 + lr) * DIM + pc;
  const unsigned short* gB1 = gB0 + (size_t)16 * DIM;
  const unsigned short* gB2 = gB0 + (size_t)32 * DIM;
  const unsigned short* gB3 = gB0 + (size_t)48 * DIM;

#define STAGE(b, t)                                         \
  do {                                                      \
    unsigned short* lA_ = smem + (b) * 12288 + wave * 1024; \
    unsigned short* lB_ = smem + (b) * 12288 + 4096 + wave * 2048; \
    int ko_ = (t) * 32;                                     \
    gload_lds16(gA0 + ko_, lA_);                            \
    gload_lds16(gA1 + ko_, lA_ + 512);                      \
    gload_lds16(gB0 + ko_, lB_);                            \
    gload_lds16(gB1 + ko_, lB_ + 512);                      \
    gload_lds16(gB2 + ko_, lB_ + 1024);                     \
    gload_lds16(gB3 + ko_, lB_ + 1536);                     \
  } while (0)

  STAGE(0, 0);
  STAGE(1, 1);
  STAGE(2, 2);
  asm volatile("s_waitcnt vmcnt(12)" ::: "memory");  // tile 0 landed
  FENCE_BAR();

  int rsw = ((lane & 15) >> 1) & 3;      // read swizzle
  int rchunk = ((lane >> 4) ^ rsw) * 8;  // physical chunk offset (shorts)

  int cur = 0;
  for (int t = 0; t < DIM / 32; ++t) {
    const unsigned short* At = smem + cur * 12288;
    const unsigned short* Bt = At + 4096;

    bf16x8 af[4], bfr[8];
#pragma unroll
    for (int m = 0; m < 4; ++m) {
      int rA = wr * 64 + m * 16 + (lane & 15);
      af[m] = *(const bf16x8*)(At + rA * 32 + rchunk);
    }
#pragma unroll
    for (int n = 0; n < 8; ++n) {
      int rB = wc * 128 + n * 16 + (lane & 15);
      bfr[n] = *(const bf16x8*)(Bt + rB * 32 + rchunk);
    }
#pragma unroll
    for (int m = 0; m < 4; ++m)
#pragma unroll
      for (int n = 0; n < 8; ++n)
        acc[m][n] = __builtin_amdgcn_mfma_f32_16x16x32_bf16(af[m], bfr[n], acc[m][n], 0, 0, 0);

    FENCE_BAR();  // all waves done reading buf[cur]
    if (t + 3 < DIM / 32) {
      STAGE(cur, t + 3);
      asm volatile("s_waitcnt vmcnt(12)" ::: "memory");  // tile t+1 landed
    } else {
      asm volatile("s_waitcnt vmcnt(0)" ::: "memory");  // drain tail
    }
    FENCE_BAR();  // tile t+1 visible
    cur = (cur == 2) ? 0 : cur + 1;
  }
#undef STAGE

  // epilogue: quantize fp32 -> u8 bucket key, repack through LDS, 16B stores.
  // C layout: col=lane&15, row=(lane>>4)*4+e. Self-sim (gr==gc) -> key 0.
  unsigned char* osh = (unsigned char*)smem;  // [64][256] bytes
#pragma unroll
  for (int h = 0; h < 2; ++h) {
    if (wr == h) {
#pragma unroll
      for (int m = 0; m < 4; ++m)
#pragma unroll
        for (int n = 0; n < 8; ++n)
#pragma unroll
          for (int e = 0; e < 4; ++e) {
            int r = m * 16 + (lane >> 4) * 4 + e;      // 0..63
            int cc = wc * 128 + n * 16 + (lane & 15);  // 0..255
            int b = (int)fmaf(acc[m][n][e], 426.6667f, 128.0f);
            b = min(max(b, 0), 255);
            int gr = bm * 128 + h * 64 + r;
            int gc = bn * 256 + cc;
            osh[r * 256 + cc] = (unsigned char)((gr == gc) ? 0 : b);
          }
    }
    __syncthreads();
#pragma unroll
    for (int it = 0; it < 4; ++it) {
      int idx = it * 4096 + tid * 16;
      int r = idx >> 8, cc = idx & 255;
      uint4 val = *(const uint4*)(osh + idx);
      *(uint4*)(S + (size_t)(bm * 128 + h * 64 + r) * TOT + bn * 256 + cc) = val;
    }
    __syncthreads();
  }
}

// ---------------- fused per-row hist + threshold scan ---------------------
// bucket = u8 key; 4 per-wave (cnt|same<<16) copies; serial 256-bucket scan.
__global__ __launch_bounds__(256) void select_kernel(
    const unsigned char* __restrict__ S, const int* __restrict__ gt,
    const unsigned int* __restrict__ lab4, float* __restrict__ rowres) {
  int row = blockIdx.x;
  int tid = threadIdx.x;
  __shared__ unsigned int h[4 * HST];
  for (int i = tid; i < 4 * HST; i += 256) h[i] = 0;
  __syncthreads();
  unsigned int* hw = h + (tid >> 6) * HST;
  unsigned int myLbl = (unsigned int)gt[row] & 0xFu;
  const unsigned char* Sr = S + (size_t)row * TOT;
  const int NV = TOT / 16;  // 4160 16B chunks
  for (int iv = tid; iv < NV; iv += 256) {
    uint4 v = *(const uint4*)(Sr + iv * 16);
    uint2 lw2 = *(const uint2*)(lab4 + iv * 2);
    unsigned int words[4] = {v.x, v.y, v.z, v.w};
#pragma unroll
    for (int wd = 0; wd < 4; ++wd) {
      unsigned int wv = words[wd];
      unsigned int lw = (wd < 2) ? lw2.x : lw2.y;
      int sh = (wd & 1) * 16;
#pragma unroll
      for (int e = 0; e < 4; ++e) {
        unsigned int b = (wv >> (8 * e)) & 0xFFu;
        unsigned int lbl = (lw >> (sh + 4 * e)) & 0xFu;
        unsigned int inc = (lbl == myLbl) ? 0x10001u : 1u;
        atomicAdd(&hw[b], inc);  // self was masked to key 0 by gemm
      }
    }
  }
  __syncthreads();
  if (tid == 0) {
    unsigned int cum = 0, same = 0;
    float res = 0.f;
    for (int b = 255; b >= 0; --b) {
      unsigned int vv = h[b] + h[b + HST] + h[b + 2 * HST] + h[b + 3 * HST];
      unsigned int cb = vv & 0xFFFFu, sb = vv >> 16;
      if (cum + cb >= (unsigned)K_SEL) {
        unsigned int need = (unsigned)K_SEL - cum;
        res = (float)same + (float)sb * ((float)need / (float)cb);
        break;
      }
      cum += cb;
      same += sb;
    }
    rowres[row] = res;
  }
}

// ---------------- final reduction ----------------------------------------
__global__ __launch_bounds__(256) void final_kernel(const float* __restrict__ rowres,
                                                    float* __restrict__ out) {
  int tid = threadIdx.x;
  float s = 0.f;
  for (int i = tid; i < NQ; i += 256) s += rowres[i];
  for (int off = 32; off; off >>= 1) s += __shfl_down(s, off);
  __shared__ float part[4];
  if ((tid & 63) == 0) part[tid >> 6] = s;
  __syncthreads();
  if (tid == 0) {
    float total = part[0] + part[1] + part[2] + part[3];
    out[0] = 1.0f - total / ((float)NQ * (float)K_SEL);
  }
}

extern "C" void kernel_launch(void* const* d_in, const int* in_sizes, int n_in,
                              void* d_out, int out_size, void* d_ws, size_t ws_size,
                              hipStream_t stream) {
  const float* inputs = (const float*)d_in[0];
  const int* gt = (const int*)d_in[1];
  const float* bank = (const float*)d_in[2];
  const int* bl = (const int*)d_in[3];
  float* out = (float*)d_out;

  char* ws = (char*)d_ws;
  const size_t F_OFF = 0;
  const size_t F_BYTES = (size_t)TOT * DIM * 2;  // 68,157,440
  const size_t S_OFF = F_OFF + F_BYTES;
  const size_t S_BYTES = (size_t)NQ * TOT;  // 68,157,440 (u8 keys)
  const size_t RR_OFF = S_OFF + S_BYTES;
  const size_t RR_BYTES = (size_t)NQ * 4;
  const size_t L4_OFF = RR_OFF + RR_BYTES;

  unsigned short* F = (unsigned short*)(ws + F_OFF);
  unsigned char* S = (unsigned char*)(ws + S_OFF);
  float* rowres = (float*)(ws + RR_OFF);
  unsigned int* lab4 = (unsigned int*)(ws + L4_OFF);

  norm_kernel<<<TOT / 4, 256, 0, stream>>>(inputs, bank, F);
  pack_kernel<<<(TOT / 8 + 255) / 256, 256, 0, stream>>>(gt, bl, lab4);
  gemm_kernel<<<(NQ / 128) * (TOT / 256), 256, 0, stream>>>(F, S);
  select_kernel<<<NQ, 256, 0, stream>>>(S, gt, lab4, rowres);
  final_kernel<<<1, 256, 0, stream>>>(rowres, out);
}

// Round 8
// 174.242 us; speedup vs baseline: 1.0742x; 1.0742x over previous
//
#include <hip/hip_runtime.h>
#include <hip/hip_bf16.h>

#define TOT 66560
#define NQ 1024
#define DIM 512
#define K_SEL 3328
#define HST 260  // per-wave u8-hist copy stride (u32)

typedef short bf16x8 __attribute__((ext_vector_type(8)));
typedef float f32x4 __attribute__((ext_vector_type(4)));

__device__ __forceinline__ unsigned short f2bf(float f) {
  unsigned int u = __float_as_uint(f);
  unsigned int r = u + 0x7FFFu + ((u >> 16) & 1u);
  return (unsigned short)(r >> 16);
}

__device__ __forceinline__ void gload_lds16(const unsigned short* g, unsigned short* l) {
  __builtin_amdgcn_global_load_lds(
      (const __attribute__((address_space(1))) unsigned int*)g,
      (__attribute__((address_space(3))) unsigned int*)l, 16, 0, 0);
}

// fence-protected barrier (rule #18)
#define FENCE_BAR()                    \
  do {                                 \
    __builtin_amdgcn_sched_barrier(0); \
    __builtin_amdgcn_s_barrier();      \
    __builtin_amdgcn_sched_barrier(0); \
  } while (0)

// ---------------- normalize rows -> bf16 feature matrix F (TOT x 512) -----
__global__ __launch_bounds__(256) void norm_kernel(
    const float* __restrict__ inputs, const float* __restrict__ bank,
    unsigned short* __restrict__ F) {
  int row = blockIdx.x * 4 + (threadIdx.x >> 6);
  int lane = threadIdx.x & 63;
  const float* src = (row < NQ) ? (inputs + (size_t)row * DIM)
                                : (bank + (size_t)(row - NQ) * DIM);
  const float4 a = *(const float4*)(src + lane * 8);
  const float4 b = *(const float4*)(src + lane * 8 + 4);
  float ss = a.x * a.x + a.y * a.y + a.z * a.z + a.w * a.w +
             b.x * b.x + b.y * b.y + b.z * b.z + b.w * b.w;
#pragma unroll
  for (int off = 1; off < 64; off <<= 1) ss += __shfl_xor(ss, off);
  float inv = 1.0f / fmaxf(sqrtf(ss), 1e-12f);
  bf16x8 o;
  o[0] = (short)f2bf(a.x * inv);
  o[1] = (short)f2bf(a.y * inv);
  o[2] = (short)f2bf(a.z * inv);
  o[3] = (short)f2bf(a.w * inv);
  o[4] = (short)f2bf(b.x * inv);
  o[5] = (short)f2bf(b.y * inv);
  o[6] = (short)f2bf(b.z * inv);
  o[7] = (short)f2bf(b.w * inv);
  *(bf16x8*)(F + (size_t)row * DIM + lane * 8) = o;
}

// ---------------- pack labels to 4-bit nibbles (C=7 fits) -----------------
__global__ __launch_bounds__(256) void pack_kernel(
    const int* __restrict__ gt, const int* __restrict__ bl,
    unsigned int* __restrict__ lab4) {
  int i = blockIdx.x * 256 + threadIdx.x;  // packs labels [8i, 8i+8)
  if (i >= TOT / 8) return;
  unsigned int w = 0;
#pragma unroll
  for (int e = 0; e < 8; ++e) {
    int c = i * 8 + e;
    int l = (c < NQ) ? gt[c] : bl[c - NQ];
    w |= ((unsigned int)l & 0xFu) << (4 * e);
  }
  lab4[i] = w;
}

// ---------------- S = quantize_u8(F[0:1024] * F^T) ------------------------
// 256x256 tile, 8 waves (2M x 4N), wave tile 128x64 -> acc[8][4], 32 MFMA
// per 32-K step. 2-deep global_load_lds pipeline (counted vmcnt(4)),
// chunk-XOR swizzle, epilogue quantizes to u8 bucket keys (self -> 0).
__global__ __launch_bounds__(512, 2) void gemm_kernel(
    const unsigned short* __restrict__ F, unsigned char* __restrict__ S) {
  __shared__ unsigned short smem[32768];  // 2 x (At[256*32]=8192 | Bt[256*32]=8192)

  // XCD-aware swizzle: 1040 blocks, 8 XCDs, 130 per XCD, bm fastest.
  int wgid = blockIdx.x;
  int xcd = wgid & 7;
  int local = wgid >> 3;
  int gid = xcd * 130 + local;
  int bm = gid & 3;   // row tile 0..3 (fastest: 4 blocks share a B panel)
  int bn = gid >> 2;  // col tile 0..259

  int tid = threadIdx.x;
  int lane = tid & 63, wave = tid >> 6;  // wave 0..7
  int wr = wave >> 2, wc = wave & 3;     // wave tile (128M x 64N)

  f32x4 acc[8][4];
#pragma unroll
  for (int m = 0; m < 8; ++m)
#pragma unroll
    for (int n = 0; n < 4; ++n) acc[m][n] = (f32x4){0.f, 0.f, 0.f, 0.f};

  int rowA0 = bm * 256;
  int rowB0 = bn * 256;
  int lr = lane >> 2;       // staged row within 16-row chunk
  int lc = lane & 3;        // logical 16B chunk
  int ssw = (lr >> 1) & 3;  // stage swizzle (row&15 derived)
  int pc = (lc ^ ssw) * 8;  // pre-swizzled global chunk offset (shorts)

  // wave w stages A rows [32w,32w+32) and B rows [32w,32w+32)
  const unsigned short* gA0 = F + (size_t)(rowA0 + wave * 32 + lr) * DIM + pc;
  const unsigned short* gA1 = gA0 + (size_t)16 * DIM;
  const unsigned short* gB0 = F + (size_t)(rowB0 + wave * 32 + lr) * DIM + pc;
  const unsigned short* gB1 = gB0 + (size_t)16 * DIM;

#define STAGE(b, t)                                         \
  do {                                                      \
    unsigned short* lA_ = smem + (b) * 16384 + wave * 1024; \
    unsigned short* lB_ = lA_ + 8192;                       \
    int ko_ = (t) * 32;                                     \
    gload_lds16(gA0 + ko_, lA_);                            \
    gload_lds16(gA1 + ko_, lA_ + 512);                      \
    gload_lds16(gB0 + ko_, lB_);                            \
    gload_lds16(gB1 + ko_, lB_ + 512);                      \
  } while (0)

  STAGE(0, 0);
  STAGE(1, 1);
  asm volatile("s_waitcnt vmcnt(4)" ::: "memory");  // tile 0 landed
  FENCE_BAR();

  int rsw = ((lane & 15) >> 1) & 3;      // read swizzle (row&15 derived)
  int rchunk = ((lane >> 4) ^ rsw) * 8;  // physical chunk offset (shorts)

  int cur = 0;
  for (int t = 0; t < DIM / 32; ++t) {
    const unsigned short* At = smem + cur * 16384;
    const unsigned short* Bt = At + 8192;

    bf16x8 af[8], bfr[4];
#pragma unroll
    for (int m = 0; m < 8; ++m) {
      int rA = wr * 128 + m * 16 + (lane & 15);
      af[m] = *(const bf16x8*)(At + rA * 32 + rchunk);
    }
#pragma unroll
    for (int n = 0; n < 4; ++n) {
      int rB = wc * 64 + n * 16 + (lane & 15);
      bfr[n] = *(const bf16x8*)(Bt + rB * 32 + rchunk);
    }
#pragma unroll
    for (int m = 0; m < 8; ++m)
#pragma unroll
      for (int n = 0; n < 4; ++n)
        acc[m][n] = __builtin_amdgcn_mfma_f32_16x16x32_bf16(af[m], bfr[n], acc[m][n], 0, 0, 0);

    FENCE_BAR();  // all waves done reading buf[cur]
    if (t + 2 < DIM / 32) {
      STAGE(cur, t + 2);
      asm volatile("s_waitcnt vmcnt(4)" ::: "memory");  // tile t+1 landed
    } else {
      asm volatile("s_waitcnt vmcnt(0)" ::: "memory");  // drain tail
    }
    FENCE_BAR();  // tile t+1 visible
    cur ^= 1;
  }
#undef STAGE

  // epilogue: quantize fp32 -> u8 bucket key, repack through LDS, 16B stores.
  // C layout: col=lane&15, row=(lane>>4)*4+e. Self-sim (gr==gc) -> key 0.
  unsigned char* osh = (unsigned char*)smem;  // [128][256] bytes = 32KB
#pragma unroll
  for (int h = 0; h < 2; ++h) {
    if (wr == h) {
#pragma unroll
      for (int m = 0; m < 8; ++m)
#pragma unroll
        for (int n = 0; n < 4; ++n)
#pragma unroll
          for (int e = 0; e < 4; ++e) {
            int r = m * 16 + (lane >> 4) * 4 + e;     // 0..127
            int cc = wc * 64 + n * 16 + (lane & 15);  // 0..255
            int b = (int)fmaf(acc[m][n][e], 426.6667f, 128.0f);
            b = min(max(b, 0), 255);
            int gr = bm * 256 + h * 128 + r;
            int gc = bn * 256 + cc;
            osh[r * 256 + cc] = (unsigned char)((gr == gc) ? 0 : b);
          }
    }
    __syncthreads();
#pragma unroll
    for (int it = 0; it < 4; ++it) {
      int idx = it * 8192 + tid * 16;
      int r = idx >> 8, cc = idx & 255;
      uint4 val = *(const uint4*)(osh + idx);
      *(uint4*)(S + (size_t)(bm * 256 + h * 128 + r) * TOT + bn * 256 + cc) = val;
    }
    __syncthreads();
  }
}

// ---------------- per-(row,seg) u8 histogram -------------------------------
// bucket = u8 key; 4 per-wave (cnt|same<<16) copies; partials to ph.
__global__ __launch_bounds__(256) void select_kernel(
    const unsigned char* __restrict__ S, const int* __restrict__ gt,
    const unsigned int* __restrict__ lab4, unsigned int* __restrict__ ph) {
  int row = blockIdx.x;
  int seg = blockIdx.y;
  int tid = threadIdx.x;
  __shared__ unsigned int h[4 * HST];
  for (int i = tid; i < 4 * HST; i += 256) h[i] = 0;
  __syncthreads();
  unsigned int* hw = h + (tid >> 6) * HST;
  unsigned int myLbl = (unsigned int)gt[row] & 0xFu;
  const unsigned char* Sr = S + (size_t)row * TOT + (size_t)seg * (TOT / 2);
  const int NV = TOT / 2 / 16;  // 2080 16B chunks
  int lbase = seg * (TOT / 2 / 8);
  for (int iv = tid; iv < NV; iv += 256) {
    uint4 v = *(const uint4*)(Sr + iv * 16);
    uint2 lw2 = *(const uint2*)(lab4 + lbase + iv * 2);
    unsigned int words[4] = {v.x, v.y, v.z, v.w};
#pragma unroll
    for (int wd = 0; wd < 4; ++wd) {
      unsigned int wv = words[wd];
      unsigned int lw = (wd < 2) ? lw2.x : lw2.y;
      int sh = (wd & 1) * 16;
#pragma unroll
      for (int e = 0; e < 4; ++e) {
        unsigned int b = (wv >> (8 * e)) & 0xFFu;
        unsigned int lbl = (lw >> (sh + 4 * e)) & 0xFu;
        unsigned int inc = (lbl == myLbl) ? 0x10001u : 1u;
        atomicAdd(&hw[b], inc);  // self was masked to key 0 by gemm
      }
    }
  }
  __syncthreads();
  unsigned int* p = ph + ((size_t)row * 2 + seg) * 256;
  for (int i = tid; i < 256; i += 256)
    p[i] = h[i] + h[i + HST] + h[i + 2 * HST] + h[i + 3 * HST];
}

// ---------------- merge partials + threshold scan --------------------------
__global__ __launch_bounds__(256) void thresh_kernel(
    const unsigned int* __restrict__ ph, float* __restrict__ rowres) {
  int row = blockIdx.x;
  int tid = threadIdx.x;
  __shared__ unsigned int h[256];
  h[tid] = ph[((size_t)row * 2 + 0) * 256 + tid] + ph[((size_t)row * 2 + 1) * 256 + tid];
  __syncthreads();
  if (tid == 0) {
    unsigned int cum = 0, same = 0;
    float res = 0.f;
    for (int b = 255; b >= 0; --b) {
      unsigned int vv = h[b];
      unsigned int cb = vv & 0xFFFFu, sb = vv >> 16;
      if (cum + cb >= (unsigned)K_SEL) {
        unsigned int need = (unsigned)K_SEL - cum;
        res = (float)same + (float)sb * ((float)need / (float)cb);
        break;
      }
      cum += cb;
      same += sb;
    }
    rowres[row] = res;
  }
}

// ---------------- final reduction ----------------------------------------
__global__ __launch_bounds__(256) void final_kernel(const float* __restrict__ rowres,
                                                    float* __restrict__ out) {
  int tid = threadIdx.x;
  float s = 0.f;
  for (int i = tid; i < NQ; i += 256) s += rowres[i];
  for (int off = 32; off; off >>= 1) s += __shfl_down(s, off);
  __shared__ float part[4];
  if ((tid & 63) == 0) part[tid >> 6] = s;
  __syncthreads();
  if (tid == 0) {
    float total = part[0] + part[1] + part[2] + part[3];
    out[0] = 1.0f - total / ((float)NQ * (float)K_SEL);
  }
}

extern "C" void kernel_launch(void* const* d_in, const int* in_sizes, int n_in,
                              void* d_out, int out_size, void* d_ws, size_t ws_size,
                              hipStream_t stream) {
  const float* inputs = (const float*)d_in[0];
  const int* gt = (const int*)d_in[1];
  const float* bank = (const float*)d_in[2];
  const int* bl = (const int*)d_in[3];
  float* out = (float*)d_out;

  char* ws = (char*)d_ws;
  const size_t F_OFF = 0;
  const size_t F_BYTES = (size_t)TOT * DIM * 2;  // 68,157,440
  const size_t S_OFF = F_OFF + F_BYTES;
  const size_t S_BYTES = (size_t)NQ * TOT;  // 68,157,440 (u8 keys)
  const size_t PH_OFF = S_OFF + S_BYTES;
  const size_t PH_BYTES = (size_t)NQ * 2 * 256 * 4;  // 2,097,152
  const size_t RR_OFF = PH_OFF + PH_BYTES;
  const size_t RR_BYTES = (size_t)NQ * 4;
  const size_t L4_OFF = RR_OFF + RR_BYTES;

  unsigned short* F = (unsigned short*)(ws + F_OFF);
  unsigned char* S = (unsigned char*)(ws + S_OFF);
  unsigned int* ph = (unsigned int*)(ws + PH_OFF);
  float* rowres = (float*)(ws + RR_OFF);
  unsigned int* lab4 = (unsigned int*)(ws + L4_OFF);

  norm_kernel<<<TOT / 4, 256, 0, stream>>>(inputs, bank, F);
  pack_kernel<<<(TOT / 8 + 255) / 256, 256, 0, stream>>>(gt, bl, lab4);
  gemm_kernel<<<(NQ / 256) * (TOT / 256), 512, 0, stream>>>(F, S);
  select_kernel<<<dim3(NQ, 2), 256, 0, stream>>>(S, gt, lab4, ph);
  thresh_kernel<<<NQ, 256, 0, stream>>>(ph, rowres);
  final_kernel<<<1, 256, 0, stream>>>(rowres, out);
}

// Round 9
// 171.315 us; speedup vs baseline: 1.0925x; 1.0171x over previous
//
#include <hip/hip_runtime.h>
#include <hip/hip_bf16.h>

#define TOT 66560
#define NQ 1024
#define DIM 512
#define K_SEL 3328
#define HST 260  // per-wave u8-hist copy stride (u32)

typedef short bf16x8 __attribute__((ext_vector_type(8)));
typedef float f32x4 __attribute__((ext_vector_type(4)));

__device__ __forceinline__ unsigned short f2bf(float f) {
  unsigned int u = __float_as_uint(f);
  unsigned int r = u + 0x7FFFu + ((u >> 16) & 1u);
  return (unsigned short)(r >> 16);
}

__device__ __forceinline__ void gload_lds16(const unsigned short* g, unsigned short* l) {
  __builtin_amdgcn_global_load_lds(
      (const __attribute__((address_space(1))) unsigned int*)g,
      (__attribute__((address_space(3))) unsigned int*)l, 16, 0, 0);
}

// fence-protected barrier (rule #18)
#define FENCE_BAR()                    \
  do {                                 \
    __builtin_amdgcn_sched_barrier(0); \
    __builtin_amdgcn_s_barrier();      \
    __builtin_amdgcn_sched_barrier(0); \
  } while (0)

// ---------------- normalize rows -> bf16 feature matrix F (TOT x 512) -----
__global__ __launch_bounds__(256) void norm_kernel(
    const float* __restrict__ inputs, const float* __restrict__ bank,
    unsigned short* __restrict__ F) {
  int row = blockIdx.x * 4 + (threadIdx.x >> 6);
  int lane = threadIdx.x & 63;
  const float* src = (row < NQ) ? (inputs + (size_t)row * DIM)
                                : (bank + (size_t)(row - NQ) * DIM);
  const float4 a = *(const float4*)(src + lane * 8);
  const float4 b = *(const float4*)(src + lane * 8 + 4);
  float ss = a.x * a.x + a.y * a.y + a.z * a.z + a.w * a.w +
             b.x * b.x + b.y * b.y + b.z * b.z + b.w * b.w;
#pragma unroll
  for (int off = 1; off < 64; off <<= 1) ss += __shfl_xor(ss, off);
  float inv = 1.0f / fmaxf(sqrtf(ss), 1e-12f);
  bf16x8 o;
  o[0] = (short)f2bf(a.x * inv);
  o[1] = (short)f2bf(a.y * inv);
  o[2] = (short)f2bf(a.z * inv);
  o[3] = (short)f2bf(a.w * inv);
  o[4] = (short)f2bf(b.x * inv);
  o[5] = (short)f2bf(b.y * inv);
  o[6] = (short)f2bf(b.z * inv);
  o[7] = (short)f2bf(b.w * inv);
  *(bf16x8*)(F + (size_t)row * DIM + lane * 8) = o;
}

// ---------------- pack labels to 4-bit nibbles (C=7 fits) -----------------
__global__ __launch_bounds__(256) void pack_kernel(
    const int* __restrict__ gt, const int* __restrict__ bl,
    unsigned int* __restrict__ lab4) {
  int i = blockIdx.x * 256 + threadIdx.x;  // packs labels [8i, 8i+8)
  if (i >= TOT / 8) return;
  unsigned int w = 0;
#pragma unroll
  for (int e = 0; e < 8; ++e) {
    int c = i * 8 + e;
    int l = (c < NQ) ? gt[c] : bl[c - NQ];
    w |= ((unsigned int)l & 0xFu) << (4 * e);
  }
  lab4[i] = w;
}

// ---------------- S = quantize_u8(F[0:1024] * F^T) ------------------------
// 256x256 tile, 8 waves (2M x 4N), wave tile 128x64. 16-phase K-half
// pipeline: 4 cycling LDS sub-slots (32 KB each), per phase {12 ds_read ||
// 4 gload_lds for region P+3} -> counted vmcnt(8) -> 1 barrier ->
// setprio(1) + 32 MFMA. Loads never drained to 0 in the main loop (T3+T4).
__global__ __launch_bounds__(512, 1) void gemm_kernel(
    const unsigned short* __restrict__ F, unsigned char* __restrict__ S) {
  __shared__ unsigned short smem[65536];  // 4 slots x (A[256][32] | B[256][32]) = 128 KB

  // XCD-aware swizzle: 1040 blocks, 8 XCDs, 130 per XCD, bm fastest.
  int wgid = blockIdx.x;
  int xcd = wgid & 7;
  int local = wgid >> 3;
  int gid = xcd * 130 + local;
  int bm = gid & 3;   // row tile 0..3 (fastest: 4 blocks share a B panel)
  int bn = gid >> 2;  // col tile 0..259

  int tid = threadIdx.x;
  int lane = tid & 63, wave = tid >> 6;  // wave 0..7
  int wr = wave >> 2, wc = wave & 3;     // wave tile (128M x 64N)

  f32x4 acc[8][4];
#pragma unroll
  for (int m = 0; m < 8; ++m)
#pragma unroll
    for (int n = 0; n < 4; ++n) acc[m][n] = (f32x4){0.f, 0.f, 0.f, 0.f};

  int rowA0 = bm * 256;
  int rowB0 = bn * 256;
  int lr = lane >> 2;       // staged row within 16-row chunk
  int lc = lane & 3;        // logical 16B chunk
  int ssw = (lr >> 1) & 3;  // stage swizzle ((row>>1)&3; wave*32 and +16 preserve it)
  int pc = (lc ^ ssw) * 8;  // pre-swizzled global chunk offset (shorts)

  // wave w stages A rows [32w,32w+32) and B rows [32w,32w+32) of each region
  const unsigned short* gA0 = F + (size_t)(rowA0 + wave * 32 + lr) * DIM + pc;
  const unsigned short* gA1 = gA0 + (size_t)16 * DIM;
  const unsigned short* gB0 = F + (size_t)(rowB0 + wave * 32 + lr) * DIM + pc;
  const unsigned short* gB1 = gB0 + (size_t)16 * DIM;

  // region r = K-half index 0..15 (K cols [r*32, r*32+32)), slot = r&3
#define STAGE(r)                                             \
  do {                                                       \
    unsigned short* lA_ = smem + ((r) & 3) * 16384 + wave * 1024; \
    unsigned short* lB_ = lA_ + 8192;                        \
    int ko_ = (r) * 32;                                      \
    gload_lds16(gA0 + ko_, lA_);                             \
    gload_lds16(gA1 + ko_, lA_ + 512);                       \
    gload_lds16(gB0 + ko_, lB_);                             \
    gload_lds16(gB1 + ko_, lB_ + 512);                       \
  } while (0)

  // prologue: 3 regions in flight; confirm region 0 (oldest 4 of 12)
  STAGE(0);
  STAGE(1);
  STAGE(2);
  asm volatile("s_waitcnt vmcnt(8)" ::: "memory");
  FENCE_BAR();

  int rsw = ((lane & 15) >> 1) & 3;      // read swizzle ((row>>1)&3)
  int rchunk = ((lane >> 4) ^ rsw) * 8;  // physical chunk offset (shorts)

  for (int P = 0; P < 16; ++P) {
    const unsigned short* As = smem + (P & 3) * 16384;
    const unsigned short* Bs = As + 8192;

    bf16x8 af[8], bfr[4];
#pragma unroll
    for (int m = 0; m < 8; ++m) {
      int rA = wr * 128 + m * 16 + (lane & 15);
      af[m] = *(const bf16x8*)(As + rA * 32 + rchunk);
    }
#pragma unroll
    for (int n = 0; n < 4; ++n) {
      int rB = wc * 64 + n * 16 + (lane & 15);
      bfr[n] = *(const bf16x8*)(Bs + rB * 32 + rchunk);
    }

    // stage region P+3 into the slot freed at phase P-1; counted waits:
    // vmcnt(8) confirms region P+1 landed (read next phase).
    if (P < 13) {
      STAGE(P + 3);
      asm volatile("s_waitcnt vmcnt(8)" ::: "memory");
    } else if (P == 13) {
      asm volatile("s_waitcnt vmcnt(4)" ::: "memory");
    } else {
      asm volatile("s_waitcnt vmcnt(0)" ::: "memory");
    }
    FENCE_BAR();

    __builtin_amdgcn_s_setprio(1);
#pragma unroll
    for (int m = 0; m < 8; ++m)
#pragma unroll
      for (int n = 0; n < 4; ++n)
        acc[m][n] = __builtin_amdgcn_mfma_f32_16x16x32_bf16(af[m], bfr[n], acc[m][n], 0, 0, 0);
    __builtin_amdgcn_s_setprio(0);
  }
#undef STAGE

  // epilogue: quantize fp32 -> u8 bucket key, repack through LDS, 16B stores.
  // C layout: col=lane&15, row=(lane>>4)*4+e. Self-sim (gr==gc) -> key 0.
  __syncthreads();  // all waves done with final MFMA inputs before aliasing smem
  unsigned char* osh = (unsigned char*)smem;  // [128][256] bytes = 32KB
#pragma unroll
  for (int h = 0; h < 2; ++h) {
    if (wr == h) {
#pragma unroll
      for (int m = 0; m < 8; ++m)
#pragma unroll
        for (int n = 0; n < 4; ++n)
#pragma unroll
          for (int e = 0; e < 4; ++e) {
            int r = m * 16 + (lane >> 4) * 4 + e;     // 0..127
            int cc = wc * 64 + n * 16 + (lane & 15);  // 0..255
            int b = (int)fmaf(acc[m][n][e], 426.6667f, 128.0f);
            b = min(max(b, 0), 255);
            int gr = bm * 256 + h * 128 + r;
            int gc = bn * 256 + cc;
            osh[r * 256 + cc] = (unsigned char)((gr == gc) ? 0 : b);
          }
    }
    __syncthreads();
#pragma unroll
    for (int it = 0; it < 4; ++it) {
      int idx = it * 8192 + tid * 16;
      int r = idx >> 8, cc = idx & 255;
      uint4 val = *(const uint4*)(osh + idx);
      *(uint4*)(S + (size_t)(bm * 256 + h * 128 + r) * TOT + bn * 256 + cc) = val;
    }
    __syncthreads();
  }
}

// ---------------- fused per-row hist + threshold scan ---------------------
// bucket = u8 key; 4 per-wave (cnt|same<<16) copies; serial 256-bucket scan.
__global__ __launch_bounds__(256) void select_kernel(
    const unsigned char* __restrict__ S, const int* __restrict__ gt,
    const unsigned int* __restrict__ lab4, float* __restrict__ rowres) {
  int row = blockIdx.x;
  int tid = threadIdx.x;
  __shared__ unsigned int h[4 * HST];
  for (int i = tid; i < 4 * HST; i += 256) h[i] = 0;
  __syncthreads();
  unsigned int* hw = h + (tid >> 6) * HST;
  unsigned int myLbl = (unsigned int)gt[row] & 0xFu;
  const unsigned char* Sr = S + (size_t)row * TOT;
  const int NV = TOT / 16;  // 4160 16B chunks
  for (int iv = tid; iv < NV; iv += 256) {
    uint4 v = *(const uint4*)(Sr + iv * 16);
    uint2 lw2 = *(const uint2*)(lab4 + iv * 2);
    unsigned int words[4] = {v.x, v.y, v.z, v.w};
#pragma unroll
    for (int wd = 0; wd < 4; ++wd) {
      unsigned int wv = words[wd];
      unsigned int lw = (wd < 2) ? lw2.x : lw2.y;
      int sh = (wd & 1) * 16;
#pragma unroll
      for (int e = 0; e < 4; ++e) {
        unsigned int b = (wv >> (8 * e)) & 0xFFu;
        unsigned int lbl = (lw >> (sh + 4 * e)) & 0xFu;
        unsigned int inc = (lbl == myLbl) ? 0x10001u : 1u;
        atomicAdd(&hw[b], inc);  // self was masked to key 0 by gemm
      }
    }
  }
  __syncthreads();
  if (tid == 0) {
    unsigned int cum = 0, same = 0;
    float res = 0.f;
    for (int b = 255; b >= 0; --b) {
      unsigned int vv = h[b] + h[b + HST] + h[b + 2 * HST] + h[b + 3 * HST];
      unsigned int cb = vv & 0xFFFFu, sb = vv >> 16;
      if (cum + cb >= (unsigned)K_SEL) {
        unsigned int need = (unsigned)K_SEL - cum;
        res = (float)same + (float)sb * ((float)need / (float)cb);
        break;
      }
      cum += cb;
      same += sb;
    }
    rowres[row] = res;
  }
}

// ---------------- final reduction ----------------------------------------
__global__ __launch_bounds__(256) void final_kernel(const float* __restrict__ rowres,
                                                    float* __restrict__ out) {
  int tid = threadIdx.x;
  float s = 0.f;
  for (int i = tid; i < NQ; i += 256) s += rowres[i];
  for (int off = 32; off; off >>= 1) s += __shfl_down(s, off);
  __shared__ float part[4];
  if ((tid & 63) == 0) part[tid >> 6] = s;
  __syncthreads();
  if (tid == 0) {
    float total = part[0] + part[1] + part[2] + part[3];
    out[0] = 1.0f - total / ((float)NQ * (float)K_SEL);
  }
}

extern "C" void kernel_launch(void* const* d_in, const int* in_sizes, int n_in,
                              void* d_out, int out_size, void* d_ws, size_t ws_size,
                              hipStream_t stream) {
  const float* inputs = (const float*)d_in[0];
  const int* gt = (const int*)d_in[1];
  const float* bank = (const float*)d_in[2];
  const int* bl = (const int*)d_in[3];
  float* out = (float*)d_out;

  char* ws = (char*)d_ws;
  const size_t F_OFF = 0;
  const size_t F_BYTES = (size_t)TOT * DIM * 2;  // 68,157,440
  const size_t S_OFF = F_OFF + F_BYTES;
  const size_t S_BYTES = (size_t)NQ * TOT;  // 68,157,440 (u8 keys)
  const size_t RR_OFF = S_OFF + S_BYTES;
  const size_t RR_BYTES = (size_t)NQ * 4;
  const size_t L4_OFF = RR_OFF + RR_BYTES;

  unsigned short* F = (unsigned short*)(ws + F_OFF);
  unsigned char* S = (unsigned char*)(ws + S_OFF);
  float* rowres = (float*)(ws + RR_OFF);
  unsigned int* lab4 = (unsigned int*)(ws + L4_OFF);

  norm_kernel<<<TOT / 4, 256, 0, stream>>>(inputs, bank, F);
  pack_kernel<<<(TOT / 8 + 255) / 256, 256, 0, stream>>>(gt, bl, lab4);
  gemm_kernel<<<(NQ / 256) * (TOT / 256), 512, 0, stream>>>(F, S);
  select_kernel<<<NQ, 256, 0, stream>>>(S, gt, lab4, rowres);
  final_kernel<<<1, 256, 0, stream>>>(rowres, out);
}

// Round 10
// 131.313 us; speedup vs baseline: 1.4253x; 1.3046x over previous
//
#include <hip/hip_runtime.h>
#include <hip/hip_bf16.h>

#define TOT 66560
#define NQ 1024
#define DIM 512
#define K_SEL 3328
#define HST 260  // per-wave u8-hist copy stride (u32)

typedef int i32x8 __attribute__((ext_vector_type(8)));
typedef float f32x4 __attribute__((ext_vector_type(4)));

__device__ __forceinline__ void gload_lds16(const void* g, void* l) {
  __builtin_amdgcn_global_load_lds(
      (const __attribute__((address_space(1))) unsigned int*)g,
      (__attribute__((address_space(3))) unsigned int*)l, 16, 0, 0);
}

// fence-protected barrier (rule #18)
#define FENCE_BAR()                    \
  do {                                 \
    __builtin_amdgcn_sched_barrier(0); \
    __builtin_amdgcn_s_barrier();      \
    __builtin_amdgcn_sched_barrier(0); \
  } while (0)

// ---------------- normalize rows -> fp8 e4m3 feature matrix F8 (TOT x 512)
__global__ __launch_bounds__(256) void norm_kernel(
    const float* __restrict__ inputs, const float* __restrict__ bank,
    unsigned char* __restrict__ F8) {
  int row = blockIdx.x * 4 + (threadIdx.x >> 6);
  int lane = threadIdx.x & 63;
  const float* src = (row < NQ) ? (inputs + (size_t)row * DIM)
                                : (bank + (size_t)(row - NQ) * DIM);
  const float4 a = *(const float4*)(src + lane * 8);
  const float4 b = *(const float4*)(src + lane * 8 + 4);
  float ss = a.x * a.x + a.y * a.y + a.z * a.z + a.w * a.w +
             b.x * b.x + b.y * b.y + b.z * b.z + b.w * b.w;
#pragma unroll
  for (int off = 1; off < 64; off <<= 1) ss += __shfl_xor(ss, off);
  float inv = 1.0f / fmaxf(sqrtf(ss), 1e-12f);
  // pack 8 fp8 e4m3 (OCP on gfx950) via v_cvt_pk_fp8_f32
  int w0 = __builtin_amdgcn_cvt_pk_fp8_f32(a.x * inv, a.y * inv, 0, false);
  w0 = __builtin_amdgcn_cvt_pk_fp8_f32(a.z * inv, a.w * inv, w0, true);
  int w1 = __builtin_amdgcn_cvt_pk_fp8_f32(b.x * inv, b.y * inv, 0, false);
  w1 = __builtin_amdgcn_cvt_pk_fp8_f32(b.z * inv, b.w * inv, w1, true);
  int2 o;
  o.x = w0;
  o.y = w1;
  *(int2*)(F8 + (size_t)row * DIM + lane * 8) = o;
}

// ---------------- pack labels to 4-bit nibbles (C=7 fits) -----------------
__global__ __launch_bounds__(256) void pack_kernel(
    const int* __restrict__ gt, const int* __restrict__ bl,
    unsigned int* __restrict__ lab4) {
  int i = blockIdx.x * 256 + threadIdx.x;  // packs labels [8i, 8i+8)
  if (i >= TOT / 8) return;
  unsigned int w = 0;
#pragma unroll
  for (int e = 0; e < 8; ++e) {
    int c = i * 8 + e;
    int l = (c < NQ) ? gt[c] : bl[c - NQ];
    w |= ((unsigned int)l & 0xFu) << (4 * e);
  }
  lab4[i] = w;
}

// ---------------- S = quantize_u8(F8[0:1024] * F8^T), MX-fp8 K=128 --------
// 128x128 tile, 4 waves (2x2), wave tile 64x64, acc[4][4]. BK=128 -> only 4
// K-steps (mfma_scale_f32_16x16x128_f8f6f4, unit scales). 2-buf 64KB LDS,
// counted vmcnt(8), chunk-XOR (row&7) swizzle via pre-swizzled global src.
__global__ __launch_bounds__(256) void gemm_kernel(
    const unsigned char* __restrict__ F8, unsigned char* __restrict__ S) {
  __shared__ unsigned char smem[65536];  // 2 x (A[128][128B] | B[128][128B])

  // XCD-aware swizzle: 4160 blocks, 8 XCDs, 520 per XCD, bm fastest.
  int wgid = blockIdx.x;
  int xcd = wgid & 7;
  int local = wgid >> 3;
  int gid = xcd * 520 + local;
  int bm = gid & 7;   // row tile 0..7 (fastest: 8 blocks share a B panel)
  int bn = gid >> 3;  // col tile 0..519

  int tid = threadIdx.x;
  int lane = tid & 63, wave = tid >> 6;
  int wr = wave >> 1, wc = wave & 1;

  f32x4 acc[4][4];
#pragma unroll
  for (int m = 0; m < 4; ++m)
#pragma unroll
    for (int n = 0; n < 4; ++n) acc[m][n] = (f32x4){0.f, 0.f, 0.f, 0.f};

  int rowA0 = bm * 128;
  int rowB0 = bn * 128;

  // staging: tile = [128 rows][8 chunks of 16B]; thread covers offsets
  // {tid*16 + q*4096}. LDS dest linear; global chunk = phys ^ (row&7).
#define STAGE(b, t)                                                          \
  do {                                                                       \
    unsigned char* lbase_ = smem + (b) * 32768;                              \
    _Pragma("unroll") for (int q_ = 0; q_ < 4; ++q_) {                       \
      int o_ = q_ * 4096 + tid * 16;                                         \
      int r_ = o_ >> 7;                                                      \
      int cg_ = ((o_ >> 4) & 7) ^ (r_ & 7);                                  \
      gload_lds16(F8 + (size_t)(rowA0 + r_) * DIM + (t) * 128 + cg_ * 16,    \
                  lbase_ + o_);                                              \
    }                                                                        \
    _Pragma("unroll") for (int q_ = 0; q_ < 4; ++q_) {                       \
      int o_ = q_ * 4096 + tid * 16;                                         \
      int r_ = o_ >> 7;                                                      \
      int cg_ = ((o_ >> 4) & 7) ^ (r_ & 7);                                  \
      gload_lds16(F8 + (size_t)(rowB0 + r_) * DIM + (t) * 128 + cg_ * 16,    \
                  lbase_ + 16384 + o_);                                      \
    }                                                                        \
  } while (0)

  STAGE(0, 0);
  STAGE(1, 1);
  asm volatile("s_waitcnt vmcnt(8)" ::: "memory");  // tile 0 landed
  FENCE_BAR();

  int g = lane >> 4;  // k-group 0..3 (32 k-bytes each)

  for (int t = 0; t < DIM / 128; ++t) {
    const unsigned char* At = smem + (t & 1) * 32768;
    const unsigned char* Bt = At + 16384;

    i32x8 af[4], bf[4];
#pragma unroll
    for (int m = 0; m < 4; ++m) {
      int r = wr * 64 + m * 16 + (lane & 15);
      const unsigned char* base = At + r * 128;
      int c0 = (2 * g) ^ (r & 7), c1 = (2 * g + 1) ^ (r & 7);
      uint4 lo = *(const uint4*)(base + c0 * 16);
      uint4 hi = *(const uint4*)(base + c1 * 16);
      af[m] = (i32x8){(int)lo.x, (int)lo.y, (int)lo.z, (int)lo.w,
                      (int)hi.x, (int)hi.y, (int)hi.z, (int)hi.w};
    }
#pragma unroll
    for (int n = 0; n < 4; ++n) {
      int r = wc * 64 + n * 16 + (lane & 15);
      const unsigned char* base = Bt + r * 128;
      int c0 = (2 * g) ^ (r & 7), c1 = (2 * g + 1) ^ (r & 7);
      uint4 lo = *(const uint4*)(base + c0 * 16);
      uint4 hi = *(const uint4*)(base + c1 * 16);
      bf[n] = (i32x8){(int)lo.x, (int)lo.y, (int)lo.z, (int)lo.w,
                      (int)hi.x, (int)hi.y, (int)hi.z, (int)hi.w};
    }

    __builtin_amdgcn_s_setprio(1);
#pragma unroll
    for (int m = 0; m < 4; ++m)
#pragma unroll
      for (int n = 0; n < 4; ++n)
        acc[m][n] = __builtin_amdgcn_mfma_scale_f32_16x16x128_f8f6f4(
            af[m], bf[n], acc[m][n], 0 /*cbsz: fp8*/, 0 /*blgp: fp8*/,
            0, 0x7F7F7F7F /*scale A = 1.0*/, 0, 0x7F7F7F7F /*scale B = 1.0*/);
    __builtin_amdgcn_s_setprio(0);

    FENCE_BAR();  // all waves done reading buf[t&1]
    if (t + 2 < DIM / 128) {
      STAGE(t & 1, t + 2);
      asm volatile("s_waitcnt vmcnt(8)" ::: "memory");  // tile t+1 landed
    } else if (t + 2 == DIM / 128) {
      asm volatile("s_waitcnt vmcnt(0)" ::: "memory");  // drain: tile t+1 landed
    }
    FENCE_BAR();  // tile t+1 visible
  }
#undef STAGE

  // epilogue: quantize fp32 -> u8 bucket key, repack through LDS, 16B stores.
  // C layout: col=lane&15, row=(lane>>4)*4+e (shape-determined, dtype-indep).
  __syncthreads();
  unsigned char* osh = (unsigned char*)smem;  // [64][128] bytes
#pragma unroll
  for (int h = 0; h < 2; ++h) {
    if (wr == h) {
#pragma unroll
      for (int m = 0; m < 4; ++m)
#pragma unroll
        for (int n = 0; n < 4; ++n)
#pragma unroll
          for (int e = 0; e < 4; ++e) {
            int r = m * 16 + (lane >> 4) * 4 + e;     // 0..63
            int cc = wc * 64 + n * 16 + (lane & 15);  // 0..127
            int b = (int)fmaf(acc[m][n][e], 426.6667f, 128.0f);
            b = min(max(b, 0), 255);
            int gr = bm * 128 + h * 64 + r;
            int gc = bn * 128 + cc;
            osh[r * 128 + cc] = (unsigned char)((gr == gc) ? 0 : b);
          }
    }
    __syncthreads();
#pragma unroll
    for (int it = 0; it < 2; ++it) {
      int idx = it * 4096 + tid * 16;
      int r = idx >> 7, cc = idx & 127;
      uint4 val = *(const uint4*)(osh + idx);
      *(uint4*)(S + (size_t)(bm * 128 + h * 64 + r) * TOT + bn * 128 + cc) = val;
    }
    __syncthreads();
  }
}

// ---------------- fused per-row hist + threshold scan ---------------------
// bucket = u8 key; 4 per-wave (cnt|same<<16) copies; serial 256-bucket scan.
__global__ __launch_bounds__(256) void select_kernel(
    const unsigned char* __restrict__ S, const int* __restrict__ gt,
    const unsigned int* __restrict__ lab4, float* __restrict__ rowres) {
  int row = blockIdx.x;
  int tid = threadIdx.x;
  __shared__ unsigned int h[4 * HST];
  for (int i = tid; i < 4 * HST; i += 256) h[i] = 0;
  __syncthreads();
  unsigned int* hw = h + (tid >> 6) * HST;
  unsigned int myLbl = (unsigned int)gt[row] & 0xFu;
  const unsigned char* Sr = S + (size_t)row * TOT;
  const int NV = TOT / 16;  // 4160 16B chunks
  for (int iv = tid; iv < NV; iv += 256) {
    uint4 v = *(const uint4*)(Sr + iv * 16);
    uint2 lw2 = *(const uint2*)(lab4 + iv * 2);
    unsigned int words[4] = {v.x, v.y, v.z, v.w};
#pragma unroll
    for (int wd = 0; wd < 4; ++wd) {
      unsigned int wv = words[wd];
      unsigned int lw = (wd < 2) ? lw2.x : lw2.y;
      int sh = (wd & 1) * 16;
#pragma unroll
      for (int e = 0; e < 4; ++e) {
        unsigned int b = (wv >> (8 * e)) & 0xFFu;
        unsigned int lbl = (lw >> (sh + 4 * e)) & 0xFu;
        unsigned int inc = (lbl == myLbl) ? 0x10001u : 1u;
        atomicAdd(&hw[b], inc);  // self was masked to key 0 by gemm
      }
    }
  }
  __syncthreads();
  if (tid == 0) {
    unsigned int cum = 0, same = 0;
    float res = 0.f;
    for (int b = 255; b >= 0; --b) {
      unsigned int vv = h[b] + h[b + HST] + h[b + 2 * HST] + h[b + 3 * HST];
      unsigned int cb = vv & 0xFFFFu, sb = vv >> 16;
      if (cum + cb >= (unsigned)K_SEL) {
        unsigned int need = (unsigned)K_SEL - cum;
        res = (float)same + (float)sb * ((float)need / (float)cb);
        break;
      }
      cum += cb;
      same += sb;
    }
    rowres[row] = res;
  }
}

// ---------------- final reduction ----------------------------------------
__global__ __launch_bounds__(256) void final_kernel(const float* __restrict__ rowres,
                                                    float* __restrict__ out) {
  int tid = threadIdx.x;
  float s = 0.f;
  for (int i = tid; i < NQ; i += 256) s += rowres[i];
  for (int off = 32; off; off >>= 1) s += __shfl_down(s, off);
  __shared__ float part[4];
  if ((tid & 63) == 0) part[tid >> 6] = s;
  __syncthreads();
  if (tid == 0) {
    float total = part[0] + part[1] + part[2] + part[3];
    out[0] = 1.0f - total / ((float)NQ * (float)K_SEL);
  }
}

extern "C" void kernel_launch(void* const* d_in, const int* in_sizes, int n_in,
                              void* d_out, int out_size, void* d_ws, size_t ws_size,
                              hipStream_t stream) {
  const float* inputs = (const float*)d_in[0];
  const int* gt = (const int*)d_in[1];
  const float* bank = (const float*)d_in[2];
  const int* bl = (const int*)d_in[3];
  float* out = (float*)d_out;

  char* ws = (char*)d_ws;
  const size_t F_OFF = 0;
  const size_t F_BYTES = (size_t)TOT * DIM;  // 34,078,720 (fp8)
  const size_t S_OFF = F_OFF + F_BYTES;
  const size_t S_BYTES = (size_t)NQ * TOT;  // 68,157,440 (u8 keys)
  const size_t RR_OFF = S_OFF + S_BYTES;
  const size_t RR_BYTES = 4096;
  const size_t L4_OFF = RR_OFF + RR_BYTES;

  unsigned char* F8 = (unsigned char*)(ws + F_OFF);
  unsigned char* S = (unsigned char*)(ws + S_OFF);
  float* rowres = (float*)(ws + RR_OFF);
  unsigned int* lab4 = (unsigned int*)(ws + L4_OFF);

  norm_kernel<<<TOT / 4, 256, 0, stream>>>(inputs, bank, F8);
  pack_kernel<<<(TOT / 8 + 255) / 256, 256, 0, stream>>>(gt, bl, lab4);
  gemm_kernel<<<(NQ / 128) * (TOT / 128), 256, 0, stream>>>(F8, S);
  select_kernel<<<NQ, 256, 0, stream>>>(S, gt, lab4, rowres);
  final_kernel<<<1, 256, 0, stream>>>(rowres, out);
}

// Round 11
// 95.826 us; speedup vs baseline: 1.9532x; 1.3703x over previous
//
#include <hip/hip_runtime.h>
#include <hip/hip_bf16.h>

#define TOT 66560
#define NQ 1024
#define DIM 512
#define K_SEL 3328
#define NCPY 16   // per-lane hist copies
#define CSTR 257  // copy stride (u32) -> bank spread

typedef int i32x8 __attribute__((ext_vector_type(8)));
typedef float f32x4 __attribute__((ext_vector_type(4)));

__device__ __forceinline__ void gload_lds16(const void* g, void* l) {
  __builtin_amdgcn_global_load_lds(
      (const __attribute__((address_space(1))) unsigned int*)g,
      (__attribute__((address_space(3))) unsigned int*)l, 16, 0, 0);
}

// fp4 e2m1 encode, nearest: levels {0,0.5,1,1.5,2,3,4,6} = codes 0..7, sign<<3
__device__ __forceinline__ unsigned int fp4enc(float v) {
  float a = fabsf(v);
  unsigned int idx = (a > 0.25f) + (a > 0.75f) + (a > 1.25f) + (a > 1.75f) +
                     (a > 2.5f) + (a > 3.5f) + (a > 5.0f);
  return ((v < 0.f) ? 8u : 0u) | idx;
}

// ---------------- normalize rows -> fp4 matrix F4 (TOT x 512, 256 B/row) --
// values stored as 32*x (scale baked in); 8 elems -> one u32 per lane.
__global__ __launch_bounds__(256) void norm_kernel(
    const float* __restrict__ inputs, const float* __restrict__ bank,
    unsigned int* __restrict__ F4) {
  int row = blockIdx.x * 4 + (threadIdx.x >> 6);
  int lane = threadIdx.x & 63;
  const float* src = (row < NQ) ? (inputs + (size_t)row * DIM)
                                : (bank + (size_t)(row - NQ) * DIM);
  const float4 a = *(const float4*)(src + lane * 8);
  const float4 b = *(const float4*)(src + lane * 8 + 4);
  float ss = a.x * a.x + a.y * a.y + a.z * a.z + a.w * a.w +
             b.x * b.x + b.y * b.y + b.z * b.z + b.w * b.w;
#pragma unroll
  for (int off = 1; off < 64; off <<= 1) ss += __shfl_xor(ss, off);
  float sc = 32.0f / fmaxf(sqrtf(ss), 1e-12f);
  unsigned int w = fp4enc(a.x * sc) | (fp4enc(a.y * sc) << 4) |
                   (fp4enc(a.z * sc) << 8) | (fp4enc(a.w * sc) << 12) |
                   (fp4enc(b.x * sc) << 16) | (fp4enc(b.y * sc) << 20) |
                   (fp4enc(b.z * sc) << 24) | (fp4enc(b.w * sc) << 28);
  F4[(size_t)row * 64 + lane] = w;
}

// ---------------- pack labels to 4-bit nibbles (C=7 fits) -----------------
__global__ __launch_bounds__(256) void pack_kernel(
    const int* __restrict__ gt, const int* __restrict__ bl,
    unsigned int* __restrict__ lab4) {
  int i = blockIdx.x * 256 + threadIdx.x;  // packs labels [8i, 8i+8)
  if (i >= TOT / 8) return;
  unsigned int w = 0;
#pragma unroll
  for (int e = 0; e < 8; ++e) {
    int c = i * 8 + e;
    int l = (c < NQ) ? gt[c] : bl[c - NQ];
    w |= ((unsigned int)l & 0xFu) << (4 * e);
  }
  lab4[i] = w;
}

// ---------------- S = quantize_u8(F4[0:1024] * F4^T), MX-fp4 K=128 --------
// 128x128 tile, 4 waves, wave 64x64, acc[4][4]. ENTIRE K=512 staged once
// (A 32KB + B 32KB), one barrier, then 4x16 mfma_scale fp4 with no mid-loop
// syncs. Chunk-XOR (row&15) involution on pre-swizzled global src + read.
__global__ __launch_bounds__(256, 2) void gemm_kernel(
    const unsigned char* __restrict__ F4, unsigned char* __restrict__ S) {
  __shared__ unsigned char smem[65536];  // A[128][256B] | B[128][256B]

  // XCD-aware swizzle: 4160 blocks, 8 XCDs, 520 per XCD, bm fastest.
  int wgid = blockIdx.x;
  int xcd = wgid & 7;
  int local = wgid >> 3;
  int gid = xcd * 520 + local;
  int bm = gid & 7;   // row tile 0..7 (fastest: 8 blocks share a B panel)
  int bn = gid >> 3;  // col tile 0..519

  int tid = threadIdx.x;
  int lane = tid & 63, wave = tid >> 6;
  int wr = wave >> 1, wc = wave & 1;

  f32x4 acc[4][4];
#pragma unroll
  for (int m = 0; m < 4; ++m)
#pragma unroll
    for (int n = 0; n < 4; ++n) acc[m][n] = (f32x4){0.f, 0.f, 0.f, 0.f};

  int rowA0 = bm * 128;
  int rowB0 = bn * 128;

  // stage full K: rows are 256 B (16 chunks of 16 B); LDS dest linear,
  // global chunk = phys_chunk ^ (row & 15).
#pragma unroll
  for (int q = 0; q < 8; ++q) {
    int o = q * 4096 + tid * 16;
    int r = o >> 8;
    int cg = ((o >> 4) & 15) ^ (r & 15);
    gload_lds16(F4 + (size_t)(rowA0 + r) * 256 + cg * 16, smem + o);
  }
#pragma unroll
  for (int q = 0; q < 8; ++q) {
    int o = q * 4096 + tid * 16;
    int r = o >> 8;
    int cg = ((o >> 4) & 15) ^ (r & 15);
    gload_lds16(F4 + (size_t)(rowB0 + r) * 256 + cg * 16, smem + 32768 + o);
  }
  asm volatile("s_waitcnt vmcnt(0)" ::: "memory");
  __syncthreads();

  int g = lane >> 4;  // k-group 0..3 (32 k-elems = 16 B each)
  const unsigned char* At = smem;
  const unsigned char* Bt = smem + 32768;

#pragma unroll
  for (int t = 0; t < 4; ++t) {
    i32x8 af[4], bf[4];
#pragma unroll
    for (int m = 0; m < 4; ++m) {
      int r = wr * 64 + m * 16 + (lane & 15);
      int c = (4 * t + g) ^ (r & 15);
      uint4 v = *(const uint4*)(At + r * 256 + c * 16);
      af[m] = (i32x8){(int)v.x, (int)v.y, (int)v.z, (int)v.w, 0, 0, 0, 0};
    }
#pragma unroll
    for (int n = 0; n < 4; ++n) {
      int r = wc * 64 + n * 16 + (lane & 15);
      int c = (4 * t + g) ^ (r & 15);
      uint4 v = *(const uint4*)(Bt + r * 256 + c * 16);
      bf[n] = (i32x8){(int)v.x, (int)v.y, (int)v.z, (int)v.w, 0, 0, 0, 0};
    }
#pragma unroll
    for (int m = 0; m < 4; ++m)
#pragma unroll
      for (int n = 0; n < 4; ++n)
        acc[m][n] = __builtin_amdgcn_mfma_scale_f32_16x16x128_f8f6f4(
            af[m], bf[n], acc[m][n], 4 /*cbsz: fp4*/, 4 /*blgp: fp4*/,
            0, 0x7F7F7F7F /*scale A = 1.0*/, 0, 0x7F7F7F7F /*scale B = 1.0*/);
  }

  // epilogue: acc = 1024*sim; quantize to u8 bucket, repack via LDS.
  // C layout: col=lane&15, row=(lane>>4)*4+e. Self-sim (gr==gc) -> key 0.
  __syncthreads();
  unsigned char* osh = (unsigned char*)smem;  // [64][128] bytes
#pragma unroll
  for (int h = 0; h < 2; ++h) {
    if (wr == h) {
#pragma unroll
      for (int m = 0; m < 4; ++m)
#pragma unroll
        for (int n = 0; n < 4; ++n)
#pragma unroll
          for (int e = 0; e < 4; ++e) {
            int r = m * 16 + (lane >> 4) * 4 + e;     // 0..63
            int cc = wc * 64 + n * 16 + (lane & 15);  // 0..127
            int b = (int)fmaf(acc[m][n][e], 0.41666669f, 128.0f);
            b = min(max(b, 0), 255);
            int gr = bm * 128 + h * 64 + r;
            int gc = bn * 128 + cc;
            osh[r * 128 + cc] = (unsigned char)((gr == gc) ? 0 : b);
          }
    }
    __syncthreads();
#pragma unroll
    for (int it = 0; it < 2; ++it) {
      int idx = it * 4096 + tid * 16;
      int r = idx >> 7, cc = idx & 127;
      uint4 val = *(const uint4*)(osh + idx);
      *(uint4*)(S + (size_t)(bm * 128 + h * 64 + r) * TOT + bn * 128 + cc) = val;
    }
    __syncthreads();
  }
}

// ---------------- fused per-row hist + parallel threshold ------------------
// 16 per-lane hist copies (stride 257), suffix-scan threshold find.
__global__ __launch_bounds__(256) void select_kernel(
    const unsigned char* __restrict__ S, const int* __restrict__ gt,
    const unsigned int* __restrict__ lab4, float* __restrict__ rowres) {
  int row = blockIdx.x;
  int tid = threadIdx.x;
  __shared__ unsigned int h[NCPY * CSTR];
  __shared__ unsigned int hcnt[256], hsm[256], sfc[256], sfs[256];
  for (int i = tid; i < NCPY * CSTR; i += 256) h[i] = 0;
  __syncthreads();
  unsigned int* hw = h + (tid & 15) * CSTR;
  unsigned int myLbl = (unsigned int)gt[row] & 0xFu;
  const unsigned char* Sr = S + (size_t)row * TOT;
  const int NV = TOT / 16;  // 4160 16B chunks
  for (int iv = tid; iv < NV; iv += 256) {
    uint4 v = *(const uint4*)(Sr + iv * 16);
    uint2 lw2 = *(const uint2*)(lab4 + iv * 2);
    unsigned int words[4] = {v.x, v.y, v.z, v.w};
#pragma unroll
    for (int wd = 0; wd < 4; ++wd) {
      unsigned int wv = words[wd];
      unsigned int lw = (wd < 2) ? lw2.x : lw2.y;
      int sh = (wd & 1) * 16;
#pragma unroll
      for (int e = 0; e < 4; ++e) {
        unsigned int b = (wv >> (8 * e)) & 0xFFu;
        unsigned int lbl = (lw >> (sh + 4 * e)) & 0xFu;
        unsigned int inc = (lbl == myLbl) ? 0x10001u : 1u;
        atomicAdd(&hw[b], inc);  // self was masked to key 0 by gemm
      }
    }
  }
  __syncthreads();
  // merge copies (parallel, one bucket per thread)
  unsigned int c = 0, s = 0;
#pragma unroll
  for (int k = 0; k < NCPY; ++k) {
    unsigned int v = h[k * CSTR + tid];
    c += v & 0xFFFFu;
    s += v >> 16;
  }
  hcnt[tid] = c;
  hsm[tid] = s;
  sfc[tid] = c;
  sfs[tid] = s;
  __syncthreads();
  // inclusive suffix sums over buckets (high -> low), Hillis-Steele
  for (int d = 1; d < 256; d <<= 1) {
    unsigned int ac = (tid + d < 256) ? sfc[tid + d] : 0u;
    unsigned int as = (tid + d < 256) ? sfs[tid + d] : 0u;
    __syncthreads();
    sfc[tid] += ac;
    sfs[tid] += as;
    __syncthreads();
  }
  unsigned int above = sfc[tid] - hcnt[tid];  // strictly above bucket tid
  if (sfc[tid] >= (unsigned)K_SEL && above < (unsigned)K_SEL) {
    unsigned int need = (unsigned)K_SEL - above;
    rowres[row] = (float)(sfs[tid] - hsm[tid]) +
                  (float)hsm[tid] * ((float)need / (float)hcnt[tid]);
  }
}

// ---------------- final reduction ----------------------------------------
__global__ __launch_bounds__(256) void final_kernel(const float* __restrict__ rowres,
                                                    float* __restrict__ out) {
  int tid = threadIdx.x;
  float s = 0.f;
  for (int i = tid; i < NQ; i += 256) s += rowres[i];
  for (int off = 32; off; off >>= 1) s += __shfl_down(s, off);
  __shared__ float part[4];
  if ((tid & 63) == 0) part[tid >> 6] = s;
  __syncthreads();
  if (tid == 0) {
    float total = part[0] + part[1] + part[2] + part[3];
    out[0] = 1.0f - total / ((float)NQ * (float)K_SEL);
  }
}

extern "C" void kernel_launch(void* const* d_in, const int* in_sizes, int n_in,
                              void* d_out, int out_size, void* d_ws, size_t ws_size,
                              hipStream_t stream) {
  const float* inputs = (const float*)d_in[0];
  const int* gt = (const int*)d_in[1];
  const float* bank = (const float*)d_in[2];
  const int* bl = (const int*)d_in[3];
  float* out = (float*)d_out;

  char* ws = (char*)d_ws;
  const size_t F_OFF = 0;
  const size_t F_BYTES = (size_t)TOT * 256;  // 17,039,360 (fp4)
  const size_t S_OFF = F_OFF + F_BYTES;
  const size_t S_BYTES = (size_t)NQ * TOT;  // 68,157,440 (u8 keys)
  const size_t RR_OFF = S_OFF + S_BYTES;
  const size_t RR_BYTES = 4096;
  const size_t L4_OFF = RR_OFF + RR_BYTES;

  unsigned int* F4 = (unsigned int*)(ws + F_OFF);
  unsigned char* S = (unsigned char*)(ws + S_OFF);
  float* rowres = (float*)(ws + RR_OFF);
  unsigned int* lab4 = (unsigned int*)(ws + L4_OFF);

  norm_kernel<<<TOT / 4, 256, 0, stream>>>(inputs, bank, F4);
  pack_kernel<<<(TOT / 8 + 255) / 256, 256, 0, stream>>>(gt, bl, lab4);
  gemm_kernel<<<(NQ / 128) * (TOT / 128), 256, 0, stream>>>(
      (const unsigned char*)F4, S);
  select_kernel<<<NQ, 256, 0, stream>>>(S, gt, lab4, rowres);
  final_kernel<<<1, 256, 0, stream>>>(rowres, out);
}